// Round 1
// baseline (14257.140 us; speedup 1.0000x reference)
//
#include <hip/hip_runtime.h>
#include <math.h>

#define Bsz 1024
#define Lsz 50
#define Esz 256
#define Hsz 256
#define NEGV (-1e9f)

// ============================================================
// init: copy decoder_input -> dec buffer, zero the mask + flags
// ============================================================
__global__ void init_kernel(const float* __restrict__ dec0,
                            float* __restrict__ dec,
                            int* __restrict__ mask,
                            int* __restrict__ cnts)
{
    int i = blockIdx.x * 256 + threadIdx.x;
    dec[i] = dec0[i];
    if (i < Bsz * Lsz) mask[i] = 0;
    if (i < 64) cnts[i] = 0;
}

// ============================================================
// pack the two Wq matrices k-major once:
// Wpk[((k>>2)*256 + n)*4 + (k&3)] = Wq[n][k]
// ============================================================
__global__ void pack_wq(const float* __restrict__ WqGl, const float* __restrict__ WqPt,
                        float* __restrict__ WqGlP, float* __restrict__ WqPtP)
{
    int k = blockIdx.x;
    int n = threadIdx.x;
    const float* src = blockIdx.y ? WqPt : WqGl;
    float*       dst = blockIdx.y ? WqPtP : WqGlP;
    dst[((size_t)(k >> 2) * 256 + n) * 4 + (k & 3)] = src[(size_t)n * 256 + k];
}

// ============================================================
// e-projection GEMM (one-time), unchanged.
// ============================================================
__global__ __launch_bounds__(256) void eproj_kernel(
    const float* __restrict__ A,
    const float* __restrict__ Wgl, const float* __restrict__ bgl, float* __restrict__ Egl,
    const float* __restrict__ Wpt, const float* __restrict__ bpt, float* __restrict__ Ept)
{
    __shared__ __align__(16) float As[16][68];
    __shared__ __align__(16) float Bs[16][68];
    const int tid = threadIdx.x;
    const int tx = tid & 15, ty = tid >> 4;
    const int ml = tid >> 2;
    const int kb = (tid & 3) << 2;

    const int x = blockIdx.x;
    const int xcd = x & 7;
    const int j = x >> 3;
    const int mt = xcd * 100 + (j >> 3);
    const int sel = (j >> 2) & 1;
    const int nt = j & 3;
    const float* W    = sel ? Wpt : Wgl;
    const float* bias = sel ? bpt : bgl;
    float*       Eo   = sel ? Ept : Egl;
    const int m0 = mt * 64, n0 = nt * 64;

    float4 a4 = *(const float4*)(A + (size_t)(m0 + ml) * 256 + kb);
    float4 b4 = *(const float4*)(W + (size_t)(n0 + ml) * 256 + kb);

    float acc[4][4] = {};
    for (int k0 = 0; k0 < 256; k0 += 16) {
        As[kb+0][ml] = a4.x; As[kb+1][ml] = a4.y; As[kb+2][ml] = a4.z; As[kb+3][ml] = a4.w;
        Bs[kb+0][ml] = b4.x; Bs[kb+1][ml] = b4.y; Bs[kb+2][ml] = b4.z; Bs[kb+3][ml] = b4.w;
        __syncthreads();
        int k1 = k0 + 16;
        if (k1 < 256) {
            a4 = *(const float4*)(A + (size_t)(m0 + ml) * 256 + k1 + kb);
            b4 = *(const float4*)(W + (size_t)(n0 + ml) * 256 + k1 + kb);
        }
#pragma unroll
        for (int kk = 0; kk < 16; kk++) {
            float4 av = *(const float4*)(&As[kk][ty << 2]);
            float4 bv = *(const float4*)(&Bs[kk][tx << 2]);
            float a_[4] = {av.x, av.y, av.z, av.w};
            float b_[4] = {bv.x, bv.y, bv.z, bv.w};
#pragma unroll
            for (int i = 0; i < 4; i++)
#pragma unroll
                for (int j2 = 0; j2 < 4; j2++) acc[i][j2] = fmaf(a_[i], b_[j2], acc[i][j2]);
        }
        __syncthreads();
    }
#pragma unroll
    for (int i = 0; i < 4; i++) {
        int m = m0 + (ty << 2) + i;
        int bb = m & (Bsz - 1);
        int ll = m >> 10;
#pragma unroll
        for (int j2 = 0; j2 < 4; j2++) {
            int n = n0 + (tx << 2) + j2;
            Eo[(size_t)bb * Lsz * Hsz + (size_t)ll * Hsz + n] = acc[i][j2] + bias[n];
        }
    }
}

// ============================================================
// Fallback kernels (unchanged) — used only if cooperative launch fails.
// ============================================================
__global__ __launch_bounds__(256) void lstm_fused(
    const float* __restrict__ dec, const float* __restrict__ hprev,
    const float* __restrict__ cin,
    const float* __restrict__ Wih, const float* __restrict__ Whh,
    const float* __restrict__ bih, const float* __restrict__ bhh,
    float* __restrict__ hout, float* __restrict__ cout)
{
    __shared__ __align__(16) float As[16][36];
    __shared__ __align__(16) float Bs[16][68];
    const int tid = threadIdx.x;
    const int tx = tid & 15, ty = tid >> 4;
    const int mlA = tid >> 3;
    const int kbA = (tid & 7) << 1;
    const int mlB = tid >> 2;
    const int kbB = (tid & 3) << 2;
    const int m0 = blockIdx.x * 32;
    const int hh0 = blockIdx.y * 16;
    const int wrow = ((mlB >> 4) << 8) + hh0 + (mlB & 15);
    const int pcol = ((mlB & 15) << 2) + (mlB >> 4);

    float2 a2 = *(const float2*)(dec + (size_t)(m0 + mlA) * 256 + kbA);
    float4 b4 = *(const float4*)(Wih + (size_t)wrow * 256 + kbB);

    float acc[2][4] = {};
    for (int k0 = 0; k0 < 512; k0 += 16) {
        As[kbA+0][mlA] = a2.x; As[kbA+1][mlA] = a2.y;
        Bs[kbB+0][pcol] = b4.x; Bs[kbB+1][pcol] = b4.y;
        Bs[kbB+2][pcol] = b4.z; Bs[kbB+3][pcol] = b4.w;
        __syncthreads();
        int k1 = k0 + 16;
        if (k1 < 512) {
            const float* Ap = (k1 < 256) ? dec : hprev;
            const float* Wp = (k1 < 256) ? Wih : Whh;
            int kk0 = k1 & 255;
            a2 = *(const float2*)(Ap + (size_t)(m0 + mlA) * 256 + kk0 + kbA);
            b4 = *(const float4*)(Wp + (size_t)wrow * 256 + kk0 + kbB);
        }
#pragma unroll
        for (int kk = 0; kk < 16; kk++) {
            float2 av = *(const float2*)(&As[kk][ty << 1]);
            float4 bv = *(const float4*)(&Bs[kk][tx << 2]);
            acc[0][0] = fmaf(av.x, bv.x, acc[0][0]);
            acc[0][1] = fmaf(av.x, bv.y, acc[0][1]);
            acc[0][2] = fmaf(av.x, bv.z, acc[0][2]);
            acc[0][3] = fmaf(av.x, bv.w, acc[0][3]);
            acc[1][0] = fmaf(av.y, bv.x, acc[1][0]);
            acc[1][1] = fmaf(av.y, bv.y, acc[1][1]);
            acc[1][2] = fmaf(av.y, bv.z, acc[1][2]);
            acc[1][3] = fmaf(av.y, bv.w, acc[1][3]);
        }
        __syncthreads();
    }

    const int hh = hh0 + tx;
    const float bi0 = bih[hh]       + bhh[hh];
    const float bf  = bih[256 + hh] + bhh[256 + hh];
    const float bg  = bih[512 + hh] + bhh[512 + hh];
    const float bo  = bih[768 + hh] + bhh[768 + hh];
#pragma unroll
    for (int i = 0; i < 2; i++) {
        int m = m0 + (ty << 1) + i;
        float gi = acc[i][0] + bi0;
        float gf = acc[i][1] + bf;
        float gc = acc[i][2] + bg;
        float go = acc[i][3] + bo;
        float ii = 1.0f / (1.0f + expf(-gi));
        float ff = 1.0f / (1.0f + expf(-gf));
        float oo = 1.0f / (1.0f + expf(-go));
        float c2 = ff * cin[(size_t)m * 256 + hh] + ii * tanhf(gc);
        hout[(size_t)m * 256 + hh] = oo * tanhf(c2);
        cout[(size_t)m * 256 + hh] = c2;
    }
}

__global__ __launch_bounds__(256) void attn_row(
    const float* __restrict__ h,
    const float* __restrict__ WqGlP, const float* __restrict__ glbq,
    const float* __restrict__ e_gl, const float* __restrict__ glv,
    const float* __restrict__ WqPtP, const float* __restrict__ ptbq,
    const float* __restrict__ e_pt, const float* __restrict__ ptv,
    int* __restrict__ mask, float* __restrict__ out, int t,
    float* __restrict__ dec, const float* __restrict__ emb)
{
    __shared__ __align__(16) float h_s[256];
    __shared__ __align__(16) float q_s[256];
    __shared__ __align__(16) float g_s[256];
    __shared__ float u_s[64];
    __shared__ float p_s[64];
    __shared__ int sel_s;

    const int tid = threadIdx.x;
    const int lane = tid & 63, wave = tid >> 6;
    const int b = blockIdx.x;

    h_s[tid] = h[(size_t)b * 256 + tid];
    __syncthreads();

    {
        float q = glbq[tid];
        const float4* Wp = (const float4*)WqGlP;
#pragma unroll 8
        for (int k4 = 0; k4 < 64; k4++) {
            float4 w  = Wp[(size_t)k4 * 256 + tid];
            float4 hv = ((const float4*)h_s)[k4];
            q = fmaf(hv.x, w.x, q);
            q = fmaf(hv.y, w.y, q);
            q = fmaf(hv.z, w.z, q);
            q = fmaf(hv.w, w.w, q);
        }
        q_s[tid] = q;
    }
    __syncthreads();

    const float* ebg = e_gl + (size_t)b * Lsz * 256;
    {
        const float4 q4 = ((const float4*)q_s)[lane];
        const float4 v4 = ((const float4*)glv)[lane];
#pragma unroll
        for (int lp = 0; lp < 13; lp++) {
            const int l = lp * 4 + wave;
            float x = 0.0f;
            if (l < Lsz) {
                float4 e4 = *(const float4*)(ebg + (size_t)l * 256 + (lane << 2));
                x  = v4.x * tanhf(q4.x + e4.x);
                x += v4.y * tanhf(q4.y + e4.y);
                x += v4.z * tanhf(q4.z + e4.z);
                x += v4.w * tanhf(q4.w + e4.w);
            }
#pragma unroll
            for (int o = 32; o > 0; o >>= 1) x += __shfl_xor(x, o, 64);
            if (lane == 0 && l < Lsz) u_s[l] = x;
        }
    }
    __syncthreads();

    if (wave == 0) {
        const int l = lane;
        const int ml = (l < Lsz) ? mask[b * Lsz + l] : 0;
        float logit = (l < Lsz) ? (ml ? NEGV : u_s[l]) : -1e30f;
        float m = logit;
#pragma unroll
        for (int o = 32; o > 0; o >>= 1) m = fmaxf(m, __shfl_xor(m, o, 64));
        float ex = (l < Lsz) ? expf(logit - m) : 0.0f;
        float den = ex;
#pragma unroll
        for (int o = 32; o > 0; o >>= 1) den += __shfl_xor(den, o, 64);
        if (l < Lsz) p_s[l] = ex / den;
    }
    __syncthreads();

    {
        float acc = 0.0f;
        const float* ebh = ebg + tid;
#pragma unroll
        for (int l = 0; l < Lsz; l++)
            acc = fmaf(p_s[l], ebh[(size_t)l * 256], acc);
        g_s[tid] = acc;
    }
    __syncthreads();

    {
        float p = ptbq[tid];
        const float4* Wp = (const float4*)WqPtP;
#pragma unroll 8
        for (int k4 = 0; k4 < 64; k4++) {
            float4 w  = Wp[(size_t)k4 * 256 + tid];
            float4 gv = ((const float4*)g_s)[k4];
            p = fmaf(gv.x, w.x, p);
            p = fmaf(gv.y, w.y, p);
            p = fmaf(gv.z, w.z, p);
            p = fmaf(gv.w, w.w, p);
        }
        q_s[tid] = p;
    }
    __syncthreads();

    const float* ebp = e_pt + (size_t)b * Lsz * 256;
    {
        const float4 q4 = ((const float4*)q_s)[lane];
        const float4 v4 = ((const float4*)ptv)[lane];
#pragma unroll
        for (int lp = 0; lp < 13; lp++) {
            const int l = lp * 4 + wave;
            float x = 0.0f;
            if (l < Lsz) {
                float4 e4 = *(const float4*)(ebp + (size_t)l * 256 + (lane << 2));
                x  = v4.x * tanhf(q4.x + e4.x);
                x += v4.y * tanhf(q4.y + e4.y);
                x += v4.z * tanhf(q4.z + e4.z);
                x += v4.w * tanhf(q4.w + e4.w);
            }
#pragma unroll
            for (int o = 32; o > 0; o >>= 1) x += __shfl_xor(x, o, 64);
            if (lane == 0 && l < Lsz) u_s[l] = x;
        }
    }
    __syncthreads();

    if (wave == 0) {
        const int l = lane;
        const int ml = (l < Lsz) ? mask[b * Lsz + l] : 0;
        float logit;
        if (l < Lsz) {
            float u = u_s[l];
            logit = 10.0f * tanhf(u);
            if (ml) logit = NEGV;
        } else logit = -1e30f;

        float m = logit;
#pragma unroll
        for (int o = 32; o > 0; o >>= 1) m = fmaxf(m, __shfl_xor(m, o, 64));
        float ex = (l < Lsz) ? expf(logit - m) : 0.0f;
        float den = ex;
#pragma unroll
        for (int o = 32; o > 0; o >>= 1) den += __shfl_xor(den, o, 64);

        float av = logit; int ai = (l < Lsz) ? l : 63;
#pragma unroll
        for (int o = 32; o > 0; o >>= 1) {
            float ov = __shfl_xor(av, o, 64);
            int   oi = __shfl_xor(ai, o, 64);
            if (ov > av || (ov == av && oi < ai)) { av = ov; ai = oi; }
        }
        const float lse = m + logf(den);
        if (l < Lsz)
            out[(size_t)b * Lsz * Lsz + (size_t)t * Lsz + l] = logit - lse;
        if (l == 0) {
            out[(size_t)Bsz * Lsz * Lsz + (size_t)b * Lsz + t] = (float)ai;
            sel_s = ai;
        }
        int newm = ml | (l == ai);
        unsigned long long bal = __ballot(l >= Lsz ? 1 : newm);
        int all = (bal == 0xFFFFFFFFFFFFFFFFull);
        if (l < Lsz) mask[b * Lsz + l] = (all && l == Lsz - 1) ? 0 : newm;
    }
    __syncthreads();

    {
        const int s = sel_s;
        dec[(size_t)b * 256 + tid] = emb[(size_t)s * Bsz * 256 + (size_t)b * 256 + tid];
    }
}

// ============================================================
// Persistent cooperative decode loop.
//
// 1024 blocks x 256 thr = 4 blocks/CU (exactly resident; enforced by
// __launch_bounds__(256,4)).  The problem splits into 32 independent
// 32-row pipelines: LSTM tile group g (rows 32g..32g+31) feeds attention
// rows of the same group and vice versa.  Even blocks: lstm tile (bid>>1)
// then attn row bid; odd blocks: attn row bid only.  Dataflow sync via
// per-group device-scope counters:
//   hcnt[g]   : +1 per lstm block per step  (attn waits >= 16*(t+1))
//   deccnt[g] : +1 per attn row per step    (lstm waits >= 32*t)
// Producer: __syncthreads (drains vmcnt) -> threadfence (wbL2) -> atomicAdd.
// Consumer: relaxed-atomic spin (no cache flush) -> threadfence (inv) -> barrier.
// GEMM bodies / arithmetic are verbatim from lstm_fused / attn_row ->
// bit-identical numerics.  c-state lives in registers; mask lives in LDS.
// ============================================================
__global__ __launch_bounds__(256, 4) void decode_loop(
    const float* __restrict__ h0, const float* __restrict__ c0,
    const float* __restrict__ Wih, const float* __restrict__ Whh,
    const float* __restrict__ bih, const float* __restrict__ bhh,
    const float* __restrict__ WqGlP, const float* __restrict__ glbq,
    const float* __restrict__ e_gl, const float* __restrict__ glv,
    const float* __restrict__ WqPtP, const float* __restrict__ ptbq,
    const float* __restrict__ e_pt, const float* __restrict__ ptv,
    const float* __restrict__ emb,
    float* __restrict__ hb0, float* __restrict__ hb1,
    float* __restrict__ dec, float* __restrict__ out,
    int* __restrict__ hcnt, int* __restrict__ deccnt)
{
    __shared__ __align__(16) float As[16][36];
    __shared__ __align__(16) float Bs[16][68];
    __shared__ __align__(16) float h_s[256];
    __shared__ __align__(16) float q_s[256];
    __shared__ __align__(16) float g_s[256];
    __shared__ float u_s[64];
    __shared__ float p_s[64];
    __shared__ int  mask_s[64];
    __shared__ int  sel_s;

    const int tid  = threadIdx.x;
    const int bid  = blockIdx.x;
    const int g    = bid >> 5;               // 32-row group
    const int lane = tid & 63, wave = tid >> 6;
    const bool is_lstm = (bid & 1) == 0;

    // ---- lstm-role constants (even blocks) ----
    const int lstm_id = bid >> 1;            // [0,512)
    const int tx = tid & 15, ty = tid >> 4;
    const int mlA = tid >> 3, kbA = (tid & 7) << 1;
    const int mlB = tid >> 2, kbB = (tid & 3) << 2;
    const int m0  = (lstm_id >> 4) * 32;     // == 32*g
    const int hh0 = (lstm_id & 15) * 16;
    const int wrow = ((mlB >> 4) << 8) + hh0 + (mlB & 15);
    const int pcol = ((mlB & 15) << 2) + (mlB >> 4);
    const int hh = hh0 + tx;

    float creg[2] = {0.f, 0.f};
    float bi0 = 0.f, bfv = 0.f, bgv = 0.f, bov = 0.f;
    if (is_lstm) {
        bi0 = bih[hh]       + bhh[hh];
        bfv = bih[256 + hh] + bhh[256 + hh];
        bgv = bih[512 + hh] + bhh[512 + hh];
        bov = bih[768 + hh] + bhh[768 + hh];
#pragma unroll
        for (int i = 0; i < 2; i++) {
            int m = m0 + (ty << 1) + i;
            creg[i] = c0[(size_t)m * 256 + hh];
        }
    }
    if (tid < 64) mask_s[tid] = 0;

    const float* ebg = e_gl + (size_t)bid * Lsz * 256;
    const float* ebp = e_pt + (size_t)bid * Lsz * 256;

    for (int t = 0; t < Lsz; t++) {
        float* hout = (t & 1) ? hb1 : hb0;

        if (is_lstm) {
            const float* hin = (t == 0) ? h0 : ((t & 1) ? hb0 : hb1);
            if (t > 0) {
                if (tid == 0) {
                    while (__hip_atomic_load(&deccnt[g], __ATOMIC_RELAXED,
                                             __HIP_MEMORY_SCOPE_AGENT) < 32 * t)
                        __builtin_amdgcn_s_sleep(2);
                    __threadfence();
                }
                __syncthreads();
            }

            float2 a2 = *(const float2*)(dec + (size_t)(m0 + mlA) * 256 + kbA);
            float4 b4 = *(const float4*)(Wih + (size_t)wrow * 256 + kbB);

            float acc[2][4] = {};
            for (int k0 = 0; k0 < 512; k0 += 16) {
                As[kbA+0][mlA] = a2.x; As[kbA+1][mlA] = a2.y;
                Bs[kbB+0][pcol] = b4.x; Bs[kbB+1][pcol] = b4.y;
                Bs[kbB+2][pcol] = b4.z; Bs[kbB+3][pcol] = b4.w;
                __syncthreads();
                int k1 = k0 + 16;
                if (k1 < 512) {
                    const float* Ap = (k1 < 256) ? dec : hin;
                    const float* Wp = (k1 < 256) ? Wih : Whh;
                    int kk0 = k1 & 255;
                    a2 = *(const float2*)(Ap + (size_t)(m0 + mlA) * 256 + kk0 + kbA);
                    b4 = *(const float4*)(Wp + (size_t)wrow * 256 + kk0 + kbB);
                }
#pragma unroll
                for (int kk = 0; kk < 16; kk++) {
                    float2 av = *(const float2*)(&As[kk][ty << 1]);
                    float4 bv = *(const float4*)(&Bs[kk][tx << 2]);
                    acc[0][0] = fmaf(av.x, bv.x, acc[0][0]);
                    acc[0][1] = fmaf(av.x, bv.y, acc[0][1]);
                    acc[0][2] = fmaf(av.x, bv.z, acc[0][2]);
                    acc[0][3] = fmaf(av.x, bv.w, acc[0][3]);
                    acc[1][0] = fmaf(av.y, bv.x, acc[1][0]);
                    acc[1][1] = fmaf(av.y, bv.y, acc[1][1]);
                    acc[1][2] = fmaf(av.y, bv.z, acc[1][2]);
                    acc[1][3] = fmaf(av.y, bv.w, acc[1][3]);
                }
                __syncthreads();
            }

#pragma unroll
            for (int i = 0; i < 2; i++) {
                int m = m0 + (ty << 1) + i;
                float gi = acc[i][0] + bi0;
                float gf = acc[i][1] + bfv;
                float gc = acc[i][2] + bgv;
                float go = acc[i][3] + bov;
                float ii = 1.0f / (1.0f + expf(-gi));
                float ff = 1.0f / (1.0f + expf(-gf));
                float oo = 1.0f / (1.0f + expf(-go));
                float c2 = ff * creg[i] + ii * tanhf(gc);
                creg[i] = c2;
                hout[(size_t)m * 256 + hh] = oo * tanhf(c2);
            }
            __syncthreads();
            if (tid == 0) { __threadfence(); atomicAdd(&hcnt[g], 1); }
        }

        // ---- wait for this row's h(t) ----
        if (tid == 0) {
            while (__hip_atomic_load(&hcnt[g], __ATOMIC_RELAXED,
                                     __HIP_MEMORY_SCOPE_AGENT) < 16 * (t + 1))
                __builtin_amdgcn_s_sleep(2);
            __threadfence();
        }
        __syncthreads();

        // ---- attention for row bid (verbatim attn_row body) ----
        h_s[tid] = hout[(size_t)bid * 256 + tid];
        __syncthreads();

        {
            float q = glbq[tid];
            const float4* Wp = (const float4*)WqGlP;
#pragma unroll 8
            for (int k4 = 0; k4 < 64; k4++) {
                float4 w  = Wp[(size_t)k4 * 256 + tid];
                float4 hv = ((const float4*)h_s)[k4];
                q = fmaf(hv.x, w.x, q);
                q = fmaf(hv.y, w.y, q);
                q = fmaf(hv.z, w.z, q);
                q = fmaf(hv.w, w.w, q);
            }
            q_s[tid] = q;
        }
        __syncthreads();

        {
            const float4 q4 = ((const float4*)q_s)[lane];
            const float4 v4 = ((const float4*)glv)[lane];
#pragma unroll
            for (int lp = 0; lp < 13; lp++) {
                const int l = lp * 4 + wave;
                float x = 0.0f;
                if (l < Lsz) {
                    float4 e4 = *(const float4*)(ebg + (size_t)l * 256 + (lane << 2));
                    x  = v4.x * tanhf(q4.x + e4.x);
                    x += v4.y * tanhf(q4.y + e4.y);
                    x += v4.z * tanhf(q4.z + e4.z);
                    x += v4.w * tanhf(q4.w + e4.w);
                }
#pragma unroll
                for (int o = 32; o > 0; o >>= 1) x += __shfl_xor(x, o, 64);
                if (lane == 0 && l < Lsz) u_s[l] = x;
            }
        }
        __syncthreads();

        if (wave == 0) {
            const int l = lane;
            const int ml = (l < Lsz) ? mask_s[l] : 0;
            float logit = (l < Lsz) ? (ml ? NEGV : u_s[l]) : -1e30f;
            float m = logit;
#pragma unroll
            for (int o = 32; o > 0; o >>= 1) m = fmaxf(m, __shfl_xor(m, o, 64));
            float ex = (l < Lsz) ? expf(logit - m) : 0.0f;
            float den = ex;
#pragma unroll
            for (int o = 32; o > 0; o >>= 1) den += __shfl_xor(den, o, 64);
            if (l < Lsz) p_s[l] = ex / den;
        }
        __syncthreads();

        {
            float acc = 0.0f;
            const float* ebh = ebg + tid;
#pragma unroll
            for (int l = 0; l < Lsz; l++)
                acc = fmaf(p_s[l], ebh[(size_t)l * 256], acc);
            g_s[tid] = acc;
        }
        __syncthreads();

        {
            float p = ptbq[tid];
            const float4* Wp = (const float4*)WqPtP;
#pragma unroll 8
            for (int k4 = 0; k4 < 64; k4++) {
                float4 w  = Wp[(size_t)k4 * 256 + tid];
                float4 gv = ((const float4*)g_s)[k4];
                p = fmaf(gv.x, w.x, p);
                p = fmaf(gv.y, w.y, p);
                p = fmaf(gv.z, w.z, p);
                p = fmaf(gv.w, w.w, p);
            }
            q_s[tid] = p;
        }
        __syncthreads();

        {
            const float4 q4 = ((const float4*)q_s)[lane];
            const float4 v4 = ((const float4*)ptv)[lane];
#pragma unroll
            for (int lp = 0; lp < 13; lp++) {
                const int l = lp * 4 + wave;
                float x = 0.0f;
                if (l < Lsz) {
                    float4 e4 = *(const float4*)(ebp + (size_t)l * 256 + (lane << 2));
                    x  = v4.x * tanhf(q4.x + e4.x);
                    x += v4.y * tanhf(q4.y + e4.y);
                    x += v4.z * tanhf(q4.z + e4.z);
                    x += v4.w * tanhf(q4.w + e4.w);
                }
#pragma unroll
                for (int o = 32; o > 0; o >>= 1) x += __shfl_xor(x, o, 64);
                if (lane == 0 && l < Lsz) u_s[l] = x;
            }
        }
        __syncthreads();

        if (wave == 0) {
            const int l = lane;
            const int ml = (l < Lsz) ? mask_s[l] : 0;
            float logit;
            if (l < Lsz) {
                float u = u_s[l];
                logit = 10.0f * tanhf(u);
                if (ml) logit = NEGV;
            } else logit = -1e30f;

            float m = logit;
#pragma unroll
            for (int o = 32; o > 0; o >>= 1) m = fmaxf(m, __shfl_xor(m, o, 64));
            float ex = (l < Lsz) ? expf(logit - m) : 0.0f;
            float den = ex;
#pragma unroll
            for (int o = 32; o > 0; o >>= 1) den += __shfl_xor(den, o, 64);

            float av = logit; int ai = (l < Lsz) ? l : 63;
#pragma unroll
            for (int o = 32; o > 0; o >>= 1) {
                float ov = __shfl_xor(av, o, 64);
                int   oi = __shfl_xor(ai, o, 64);
                if (ov > av || (ov == av && oi < ai)) { av = ov; ai = oi; }
            }
            const float lse = m + logf(den);
            if (l < Lsz)
                out[(size_t)bid * Lsz * Lsz + (size_t)t * Lsz + l] = logit - lse;
            if (l == 0) {
                out[(size_t)Bsz * Lsz * Lsz + (size_t)bid * Lsz + t] = (float)ai;
                sel_s = ai;
            }
            int newm = ml | (l == ai);
            unsigned long long bal = __ballot(l >= Lsz ? 1 : newm);
            int all = (bal == 0xFFFFFFFFFFFFFFFFull);
            if (l < Lsz) mask_s[l] = (all && l == Lsz - 1) ? 0 : newm;
        }
        __syncthreads();

        {
            const int s = sel_s;
            dec[(size_t)bid * 256 + tid] =
                emb[(size_t)s * Bsz * 256 + (size_t)bid * 256 + tid];
        }
        __syncthreads();
        if (tid == 0) { __threadfence(); atomicAdd(&deccnt[g], 1); }
    }
}

// ============================================================
extern "C" void kernel_launch(void* const* d_in, const int* in_sizes, int n_in,
                              void* d_out, int out_size, void* d_ws, size_t ws_size,
                              hipStream_t stream) {
    const float* decoder_input = (const float*)d_in[0];
    const float* emb           = (const float*)d_in[1];   // [L,B,E]
    const float* h0            = (const float*)d_in[2];
    const float* c0            = (const float*)d_in[3];
    const float* context       = (const float*)d_in[4];   // [L,B,H]
    const float* Wih    = (const float*)d_in[6];
    const float* Whh    = (const float*)d_in[7];
    const float* bih    = (const float*)d_in[8];
    const float* bhh    = (const float*)d_in[9];
    const float* glWq   = (const float*)d_in[10];
    const float* glbq   = (const float*)d_in[11];
    const float* glWref = (const float*)d_in[12];
    const float* glbref = (const float*)d_in[13];
    const float* glv    = (const float*)d_in[14];
    const float* ptWq   = (const float*)d_in[15];
    const float* ptbq   = (const float*)d_in[16];
    const float* ptWref = (const float*)d_in[17];
    const float* ptbref = (const float*)d_in[18];
    const float* ptv    = (const float*)d_in[19];

    float* out = (float*)d_out;

    // workspace layout (floats)
    float* ws    = (float*)d_ws;
    float* e_gl  = ws;                                    // [B,L,H]
    float* e_pt  = e_gl + (size_t)Bsz * Lsz * Hsz;        // [B,L,H]
    float* WqGlP = e_pt + (size_t)Bsz * Lsz * Hsz;        // [H,H] packed
    float* WqPtP = WqGlP + (size_t)Hsz * Hsz;
    float* hb0   = WqPtP + (size_t)Hsz * Hsz;
    float* hb1   = hb0 + (size_t)Bsz * Hsz;
    float* cb0   = hb1 + (size_t)Bsz * Hsz;
    float* cb1   = cb0 + (size_t)Bsz * Hsz;
    float* dec   = cb1 + (size_t)Bsz * Hsz;
    int*   mask  = (int*)(dec + (size_t)Bsz * Esz);       // [B,L]
    int*   cnts  = mask + (size_t)Bsz * Lsz;              // 64 flags
    int*   hcnt   = cnts;
    int*   deccnt = cnts + 32;

    init_kernel<<<dim3(Bsz), dim3(256), 0, stream>>>(decoder_input, dec, mask, cnts);
    pack_wq<<<dim3(256, 2), dim3(256), 0, stream>>>(glWq, ptWq, WqGlP, WqPtP);

    eproj_kernel<<<dim3(6400), dim3(256), 0, stream>>>(
        context, glWref, glbref, e_gl, ptWref, ptbref, e_pt);

    void* kargs[] = {
        (void*)&h0, (void*)&c0, (void*)&Wih, (void*)&Whh,
        (void*)&bih, (void*)&bhh, (void*)&WqGlP, (void*)&glbq,
        (void*)&e_gl, (void*)&glv, (void*)&WqPtP, (void*)&ptbq,
        (void*)&e_pt, (void*)&ptv, (void*)&emb,
        (void*)&hb0, (void*)&hb1, (void*)&dec, (void*)&out,
        (void*)&hcnt, (void*)&deccnt
    };
    hipError_t err = hipLaunchCooperativeKernel(
        (const void*)decode_loop, dim3(Bsz), dim3(256), kargs, 0, stream);

    if (err != hipSuccess) {
        // Fallback: per-step launch loop (previous verified path).
        float* hbuf[2] = {hb0, hb1};
        float* cbuf[2] = {cb0, cb1};
        for (int t = 0; t < Lsz; t++) {
            const float* hin = (t == 0) ? h0 : hbuf[(t + 1) & 1];
            const float* cin = (t == 0) ? c0 : cbuf[(t + 1) & 1];
            float* hout = hbuf[t & 1];
            float* cout = cbuf[t & 1];

            lstm_fused<<<dim3(32, 16), dim3(256), 0, stream>>>(
                dec, hin, cin, Wih, Whh, bih, bhh, hout, cout);

            attn_row<<<dim3(Bsz), dim3(256), 0, stream>>>(
                hout, WqGlP, glbq, e_gl, glv, WqPtP, ptbq, e_pt, ptv,
                mask, out, t, dec, emb);
        }
    }
}

// Round 2
// 6327.967 us; speedup vs baseline: 2.2530x; 2.2530x over previous
//
#include <hip/hip_runtime.h>
#include <math.h>

#define Bsz 1024
#define Lsz 50
#define Esz 256
#define Hsz 256
#define NEGV (-1e9f)

// ============================================================
// e-projection GEMM (one-time) + Wq k-major pack fused into one
// dispatch.  Blocks [0,6400): eproj exactly as the verified kernel
// (XCD-partitioned m-tiles, reg prefetch, LDS stride 68).
// Blocks [6400,6912): pack_wq (trivial, runs in eproj's shadow).
// ============================================================
__global__ __launch_bounds__(256) void eproj_pack(
    const float* __restrict__ A,
    const float* __restrict__ Wgl, const float* __restrict__ bgl, float* __restrict__ Egl,
    const float* __restrict__ Wpt, const float* __restrict__ bpt, float* __restrict__ Ept,
    const float* __restrict__ WqGl, const float* __restrict__ WqPt,
    float* __restrict__ WqGlP, float* __restrict__ WqPtP)
{
    __shared__ __align__(16) float As[16][68];
    __shared__ __align__(16) float Bs[16][68];
    const int tid = threadIdx.x;

    if (blockIdx.x >= 6400) {
        // ---- pack branch: Wpk[((k>>2)*256 + n)*4 + (k&3)] = Wq[n][k] ----
        const int p = blockIdx.x - 6400;       // [0,512)
        const int sel = p >> 8;
        const int k = p & 255;
        const float* src = sel ? WqPt : WqGl;
        float*       dst = sel ? WqPtP : WqGlP;
        dst[((size_t)(k >> 2) * 256 + tid) * 4 + (k & 3)] = src[(size_t)tid * 256 + k];
        return;
    }

    const int tx = tid & 15, ty = tid >> 4;
    const int ml = tid >> 2;
    const int kb = (tid & 3) << 2;

    const int x = blockIdx.x;
    const int xcd = x & 7;
    const int j = x >> 3;
    const int mt = xcd * 100 + (j >> 3);
    const int sel = (j >> 2) & 1;
    const int nt = j & 3;
    const float* W    = sel ? Wpt : Wgl;
    const float* bias = sel ? bpt : bgl;
    float*       Eo   = sel ? Ept : Egl;
    const int m0 = mt * 64, n0 = nt * 64;

    float4 a4 = *(const float4*)(A + (size_t)(m0 + ml) * 256 + kb);
    float4 b4 = *(const float4*)(W + (size_t)(n0 + ml) * 256 + kb);

    float acc[4][4] = {};
    for (int k0 = 0; k0 < 256; k0 += 16) {
        As[kb+0][ml] = a4.x; As[kb+1][ml] = a4.y; As[kb+2][ml] = a4.z; As[kb+3][ml] = a4.w;
        Bs[kb+0][ml] = b4.x; Bs[kb+1][ml] = b4.y; Bs[kb+2][ml] = b4.z; Bs[kb+3][ml] = b4.w;
        __syncthreads();
        int k1 = k0 + 16;
        if (k1 < 256) {
            a4 = *(const float4*)(A + (size_t)(m0 + ml) * 256 + k1 + kb);
            b4 = *(const float4*)(W + (size_t)(n0 + ml) * 256 + k1 + kb);
        }
#pragma unroll
        for (int kk = 0; kk < 16; kk++) {
            float4 av = *(const float4*)(&As[kk][ty << 2]);
            float4 bv = *(const float4*)(&Bs[kk][tx << 2]);
            float a_[4] = {av.x, av.y, av.z, av.w};
            float b_[4] = {bv.x, bv.y, bv.z, bv.w};
#pragma unroll
            for (int i = 0; i < 4; i++)
#pragma unroll
                for (int j2 = 0; j2 < 4; j2++) acc[i][j2] = fmaf(a_[i], b_[j2], acc[i][j2]);
        }
        __syncthreads();
    }
#pragma unroll
    for (int i = 0; i < 4; i++) {
        int m = m0 + (ty << 2) + i;
        int bb = m & (Bsz - 1);
        int ll = m >> 10;
#pragma unroll
        for (int j2 = 0; j2 < 4; j2++) {
            int n = n0 + (tx << 2) + j2;
            Eo[(size_t)bb * Lsz * Hsz + (size_t)ll * Hsz + n] = acc[i][j2] + bias[n];
        }
    }
}

// ============================================================
// K1: fused LSTM, 32 rows x 64 gate-cols per block -> 512 blocks.
// Verbatim from the verified 4.14ms kernel (bit-identical h/c).
// At t=0 the host passes decoder_input directly as `dec`.
// ============================================================
__global__ __launch_bounds__(256) void lstm_fused(
    const float* __restrict__ dec, const float* __restrict__ hprev,
    const float* __restrict__ cin,
    const float* __restrict__ Wih, const float* __restrict__ Whh,
    const float* __restrict__ bih, const float* __restrict__ bhh,
    float* __restrict__ hout, float* __restrict__ cout)
{
    __shared__ __align__(16) float As[16][36];
    __shared__ __align__(16) float Bs[16][68];
    const int tid = threadIdx.x;
    const int tx = tid & 15, ty = tid >> 4;
    const int mlA = tid >> 3;
    const int kbA = (tid & 7) << 1;
    const int mlB = tid >> 2;
    const int kbB = (tid & 3) << 2;
    const int m0 = blockIdx.x * 32;
    const int hh0 = blockIdx.y * 16;
    const int wrow = ((mlB >> 4) << 8) + hh0 + (mlB & 15);
    const int pcol = ((mlB & 15) << 2) + (mlB >> 4);

    float2 a2 = *(const float2*)(dec + (size_t)(m0 + mlA) * 256 + kbA);
    float4 b4 = *(const float4*)(Wih + (size_t)wrow * 256 + kbB);

    float acc[2][4] = {};
    for (int k0 = 0; k0 < 512; k0 += 16) {
        As[kbA+0][mlA] = a2.x; As[kbA+1][mlA] = a2.y;
        Bs[kbB+0][pcol] = b4.x; Bs[kbB+1][pcol] = b4.y;
        Bs[kbB+2][pcol] = b4.z; Bs[kbB+3][pcol] = b4.w;
        __syncthreads();
        int k1 = k0 + 16;
        if (k1 < 512) {
            const float* Ap = (k1 < 256) ? dec : hprev;
            const float* Wp = (k1 < 256) ? Wih : Whh;
            int kk0 = k1 & 255;
            a2 = *(const float2*)(Ap + (size_t)(m0 + mlA) * 256 + kk0 + kbA);
            b4 = *(const float4*)(Wp + (size_t)wrow * 256 + kk0 + kbB);
        }
#pragma unroll
        for (int kk = 0; kk < 16; kk++) {
            float2 av = *(const float2*)(&As[kk][ty << 1]);
            float4 bv = *(const float4*)(&Bs[kk][tx << 2]);
            acc[0][0] = fmaf(av.x, bv.x, acc[0][0]);
            acc[0][1] = fmaf(av.x, bv.y, acc[0][1]);
            acc[0][2] = fmaf(av.x, bv.z, acc[0][2]);
            acc[0][3] = fmaf(av.x, bv.w, acc[0][3]);
            acc[1][0] = fmaf(av.y, bv.x, acc[1][0]);
            acc[1][1] = fmaf(av.y, bv.y, acc[1][1]);
            acc[1][2] = fmaf(av.y, bv.z, acc[1][2]);
            acc[1][3] = fmaf(av.y, bv.w, acc[1][3]);
        }
        __syncthreads();
    }

    const int hh = hh0 + tx;
    const float bi0 = bih[hh]       + bhh[hh];
    const float bf  = bih[256 + hh] + bhh[256 + hh];
    const float bg  = bih[512 + hh] + bhh[512 + hh];
    const float bo  = bih[768 + hh] + bhh[768 + hh];
#pragma unroll
    for (int i = 0; i < 2; i++) {
        int m = m0 + (ty << 1) + i;
        float gi = acc[i][0] + bi0;
        float gf = acc[i][1] + bf;
        float gc = acc[i][2] + bg;
        float go = acc[i][3] + bo;
        float ii = 1.0f / (1.0f + expf(-gi));
        float ff = 1.0f / (1.0f + expf(-gf));
        float oo = 1.0f / (1.0f + expf(-go));
        float c2 = ff * cin[(size_t)m * 256 + hh] + ii * tanhf(gc);
        hout[(size_t)m * 256 + hh] = oo * tanhf(c2);
        cout[(size_t)m * 256 + hh] = c2;
    }
}

// ============================================================
// K2: fused glimpse + pointer attention, TWO rows per block
// -> 512 blocks.  Each loaded Wq float4 now feeds both rows'
// matvec chains (L2 Wq traffic 512->256 MB/step); u-phase waves
// {2r,2r+1} cover row r's 50 l's with zero idle slots; softmax /
// argmax run on waves 0 and 1 (one per row).  Every per-output
// FMA / reduce chain is in the exact order of the verified kernel
// -> bit-identical results.  Mask is skipped (all-zero) at t=0,
// so no init kernel is needed.
// ============================================================
__global__ __launch_bounds__(256) void attn_row2(
    const float* __restrict__ h,
    const float* __restrict__ WqGlP, const float* __restrict__ glbq,
    const float* __restrict__ e_gl, const float* __restrict__ glv,
    const float* __restrict__ WqPtP, const float* __restrict__ ptbq,
    const float* __restrict__ e_pt, const float* __restrict__ ptv,
    int* __restrict__ mask, float* __restrict__ out, int t,
    float* __restrict__ dec, const float* __restrict__ emb)
{
    __shared__ __align__(16) float h_s[2][256];
    __shared__ __align__(16) float q_s[2][256];
    __shared__ __align__(16) float g_s[2][256];
    __shared__ float u_s[2][64];
    __shared__ float p_s[2][64];
    __shared__ int  sel_s[2];

    const int tid = threadIdx.x;
    const int lane = tid & 63, wave = tid >> 6;
    const int r0 = blockIdx.x * 2, r1 = r0 + 1;

    h_s[0][tid] = h[(size_t)r0 * 256 + tid];
    h_s[1][tid] = h[(size_t)r1 * 256 + tid];
    __syncthreads();

    // ---- glimpse query matvec: one w load, two rows ----
    {
        float q0 = glbq[tid], q1 = q0;
        const float4* Wp = (const float4*)WqGlP;
#pragma unroll 8
        for (int k4 = 0; k4 < 64; k4++) {
            float4 w   = Wp[(size_t)k4 * 256 + tid];
            float4 h0v = ((const float4*)h_s[0])[k4];
            float4 h1v = ((const float4*)h_s[1])[k4];
            q0 = fmaf(h0v.x, w.x, q0);
            q0 = fmaf(h0v.y, w.y, q0);
            q0 = fmaf(h0v.z, w.z, q0);
            q0 = fmaf(h0v.w, w.w, q0);
            q1 = fmaf(h1v.x, w.x, q1);
            q1 = fmaf(h1v.y, w.y, q1);
            q1 = fmaf(h1v.z, w.z, q1);
            q1 = fmaf(h1v.w, w.w, q1);
        }
        q_s[0][tid] = q0; q_s[1][tid] = q1;
    }
    __syncthreads();

    const int urow = wave >> 1, w2 = wave & 1;   // wave pair per row
    const int rgu = r0 + urow;
    const float* ebgu = e_gl + (size_t)rgu * Lsz * 256;
    const float* ebpu = e_pt + (size_t)rgu * Lsz * 256;

    // ---- glimpse u ----
    {
        const float4 q4 = ((const float4*)q_s[urow])[lane];
        const float4 v4 = ((const float4*)glv)[lane];
#pragma unroll
        for (int lp = 0; lp < 25; lp++) {
            const int l = lp * 2 + w2;
            float4 e4 = *(const float4*)(ebgu + (size_t)l * 256 + (lane << 2));
            float x  = v4.x * tanhf(q4.x + e4.x);
            x += v4.y * tanhf(q4.y + e4.y);
            x += v4.z * tanhf(q4.z + e4.z);
            x += v4.w * tanhf(q4.w + e4.w);
#pragma unroll
            for (int o = 32; o > 0; o >>= 1) x += __shfl_xor(x, o, 64);
            if (lane == 0) u_s[urow][l] = x;
        }
    }
    __syncthreads();

    // ---- glimpse softmax (wave r handles row r) ----
    if (wave < 2) {
        const int row = wave, rg = r0 + row;
        const int l = lane;
        const int ml = (l < Lsz && t > 0) ? mask[rg * Lsz + l] : 0;
        float logit = (l < Lsz) ? (ml ? NEGV : u_s[row][l]) : -1e30f;
        float m = logit;
#pragma unroll
        for (int o = 32; o > 0; o >>= 1) m = fmaxf(m, __shfl_xor(m, o, 64));
        float ex = (l < Lsz) ? expf(logit - m) : 0.0f;
        float den = ex;
#pragma unroll
        for (int o = 32; o > 0; o >>= 1) den += __shfl_xor(den, o, 64);
        if (l < Lsz) p_s[row][l] = ex / den;
    }
    __syncthreads();

    // ---- glimpse mix (both rows per thread, ascending l) ----
    {
        float a0 = 0.0f, a1 = 0.0f;
        const float* eb0 = e_gl + (size_t)r0 * Lsz * 256 + tid;
        const float* eb1 = e_gl + (size_t)r1 * Lsz * 256 + tid;
#pragma unroll
        for (int l = 0; l < Lsz; l++) {
            a0 = fmaf(p_s[0][l], eb0[(size_t)l * 256], a0);
            a1 = fmaf(p_s[1][l], eb1[(size_t)l * 256], a1);
        }
        g_s[0][tid] = a0; g_s[1][tid] = a1;
    }
    __syncthreads();

    // ---- pointer query matvec: one w load, two rows ----
    {
        float p0 = ptbq[tid], p1 = p0;
        const float4* Wp = (const float4*)WqPtP;
#pragma unroll 8
        for (int k4 = 0; k4 < 64; k4++) {
            float4 w   = Wp[(size_t)k4 * 256 + tid];
            float4 g0v = ((const float4*)g_s[0])[k4];
            float4 g1v = ((const float4*)g_s[1])[k4];
            p0 = fmaf(g0v.x, w.x, p0);
            p0 = fmaf(g0v.y, w.y, p0);
            p0 = fmaf(g0v.z, w.z, p0);
            p0 = fmaf(g0v.w, w.w, p0);
            p1 = fmaf(g1v.x, w.x, p1);
            p1 = fmaf(g1v.y, w.y, p1);
            p1 = fmaf(g1v.z, w.z, p1);
            p1 = fmaf(g1v.w, w.w, p1);
        }
        q_s[0][tid] = p0; q_s[1][tid] = p1;
    }
    __syncthreads();

    // ---- pointer u ----
    {
        const float4 q4 = ((const float4*)q_s[urow])[lane];
        const float4 v4 = ((const float4*)ptv)[lane];
#pragma unroll
        for (int lp = 0; lp < 25; lp++) {
            const int l = lp * 2 + w2;
            float4 e4 = *(const float4*)(ebpu + (size_t)l * 256 + (lane << 2));
            float x  = v4.x * tanhf(q4.x + e4.x);
            x += v4.y * tanhf(q4.y + e4.y);
            x += v4.z * tanhf(q4.z + e4.z);
            x += v4.w * tanhf(q4.w + e4.w);
#pragma unroll
            for (int o = 32; o > 0; o >>= 1) x += __shfl_xor(x, o, 64);
            if (lane == 0) u_s[urow][l] = x;
        }
    }
    __syncthreads();

    // ---- pointer softmax + argmax + log_p + mask update ----
    if (wave < 2) {
        const int row = wave, rg = r0 + row;
        const int l = lane;
        const int ml = (l < Lsz && t > 0) ? mask[rg * Lsz + l] : 0;
        float logit;
        if (l < Lsz) {
            float u = u_s[row][l];
            logit = 10.0f * tanhf(u);
            if (ml) logit = NEGV;
        } else logit = -1e30f;

        float m = logit;
#pragma unroll
        for (int o = 32; o > 0; o >>= 1) m = fmaxf(m, __shfl_xor(m, o, 64));
        float ex = (l < Lsz) ? expf(logit - m) : 0.0f;
        float den = ex;
#pragma unroll
        for (int o = 32; o > 0; o >>= 1) den += __shfl_xor(den, o, 64);

        float av = logit; int ai = (l < Lsz) ? l : 63;
#pragma unroll
        for (int o = 32; o > 0; o >>= 1) {
            float ov = __shfl_xor(av, o, 64);
            int   oi = __shfl_xor(ai, o, 64);
            if (ov > av || (ov == av && oi < ai)) { av = ov; ai = oi; }
        }
        const float lse = m + logf(den);
        if (l < Lsz)
            out[(size_t)rg * Lsz * Lsz + (size_t)t * Lsz + l] = logit - lse;
        if (l == 0) {
            out[(size_t)Bsz * Lsz * Lsz + (size_t)rg * Lsz + t] = (float)ai;
            sel_s[row] = ai;
        }
        int newm = ml | (l == ai);
        unsigned long long bal = __ballot(l >= Lsz ? 1 : newm);
        int all = (bal == 0xFFFFFFFFFFFFFFFFull);
        if (l < Lsz) mask[rg * Lsz + l] = (all && l == Lsz - 1) ? 0 : newm;
    }
    __syncthreads();

    // ---- gather next decoder input for both rows ----
    {
        dec[(size_t)r0 * 256 + tid] =
            emb[(size_t)sel_s[0] * Bsz * 256 + (size_t)r0 * 256 + tid];
        dec[(size_t)r1 * 256 + tid] =
            emb[(size_t)sel_s[1] * Bsz * 256 + (size_t)r1 * 256 + tid];
    }
}

// ============================================================
extern "C" void kernel_launch(void* const* d_in, const int* in_sizes, int n_in,
                              void* d_out, int out_size, void* d_ws, size_t ws_size,
                              hipStream_t stream) {
    const float* decoder_input = (const float*)d_in[0];
    const float* emb           = (const float*)d_in[1];   // [L,B,E]
    const float* h0            = (const float*)d_in[2];
    const float* c0            = (const float*)d_in[3];
    const float* context       = (const float*)d_in[4];   // [L,B,H]
    const float* Wih    = (const float*)d_in[6];
    const float* Whh    = (const float*)d_in[7];
    const float* bih    = (const float*)d_in[8];
    const float* bhh    = (const float*)d_in[9];
    const float* glWq   = (const float*)d_in[10];
    const float* glbq   = (const float*)d_in[11];
    const float* glWref = (const float*)d_in[12];
    const float* glbref = (const float*)d_in[13];
    const float* glv    = (const float*)d_in[14];
    const float* ptWq   = (const float*)d_in[15];
    const float* ptbq   = (const float*)d_in[16];
    const float* ptWref = (const float*)d_in[17];
    const float* ptbref = (const float*)d_in[18];
    const float* ptv    = (const float*)d_in[19];

    float* out = (float*)d_out;

    // workspace layout (floats)
    float* ws    = (float*)d_ws;
    float* e_gl  = ws;                                    // [B,L,H]
    float* e_pt  = e_gl + (size_t)Bsz * Lsz * Hsz;        // [B,L,H]
    float* WqGlP = e_pt + (size_t)Bsz * Lsz * Hsz;        // [H,H] packed
    float* WqPtP = WqGlP + (size_t)Hsz * Hsz;
    float* hb0   = WqPtP + (size_t)Hsz * Hsz;
    float* hb1   = hb0 + (size_t)Bsz * Hsz;
    float* cb0   = hb1 + (size_t)Bsz * Hsz;
    float* cb1   = cb0 + (size_t)Bsz * Hsz;
    float* dec   = cb1 + (size_t)Bsz * Hsz;
    int*   mask  = (int*)(dec + (size_t)Bsz * Esz);       // [B,L]

    float* hbuf[2] = {hb0, hb1};
    float* cbuf[2] = {cb0, cb1};

    // one-time: e-projection GEMMs + Wq pack, single dispatch
    eproj_pack<<<dim3(6912), dim3(256), 0, stream>>>(
        context, glWref, glbref, e_gl, ptWref, ptbref, e_pt,
        glWq, ptWq, WqGlP, WqPtP);

    for (int t = 0; t < Lsz; t++) {
        const float* Ain = (t == 0) ? decoder_input : dec;
        const float* hin = (t == 0) ? h0 : hbuf[(t + 1) & 1];
        const float* cin = (t == 0) ? c0 : cbuf[(t + 1) & 1];
        float* hout = hbuf[t & 1];
        float* cout = cbuf[t & 1];

        lstm_fused<<<dim3(32, 16), dim3(256), 0, stream>>>(
            Ain, hin, cin, Wih, Whh, bih, bhh, hout, cout);

        attn_row2<<<dim3(512), dim3(256), 0, stream>>>(
            hout, WqGlP, glbq, e_gl, glv, WqPtP, ptbq, e_pt, ptv,
            mask, out, t, dec, emb);
    }
}

// Round 3
// 4391.483 us; speedup vs baseline: 3.2465x; 1.4410x over previous
//
#include <hip/hip_runtime.h>
#include <math.h>

#define Bsz 1024
#define Lsz 50
#define Esz 256
#define Hsz 256
#define NEGV (-1e9f)

// ============================================================
// e-projection GEMM (one-time) + Wq k-major pack fused into one
// dispatch.  Blocks [0,6400): eproj exactly as the verified kernel
// (XCD-partitioned m-tiles, reg prefetch, LDS stride 68).
// Blocks [6400,6912): pack_wq (trivial, runs in eproj's shadow).
// ============================================================
__global__ __launch_bounds__(256) void eproj_pack(
    const float* __restrict__ A,
    const float* __restrict__ Wgl, const float* __restrict__ bgl, float* __restrict__ Egl,
    const float* __restrict__ Wpt, const float* __restrict__ bpt, float* __restrict__ Ept,
    const float* __restrict__ WqGl, const float* __restrict__ WqPt,
    float* __restrict__ WqGlP, float* __restrict__ WqPtP)
{
    __shared__ __align__(16) float As[16][68];
    __shared__ __align__(16) float Bs[16][68];
    const int tid = threadIdx.x;

    if (blockIdx.x >= 6400) {
        // ---- pack branch: Wpk[((k>>2)*256 + n)*4 + (k&3)] = Wq[n][k] ----
        const int p = blockIdx.x - 6400;       // [0,512)
        const int sel = p >> 8;
        const int k = p & 255;
        const float* src = sel ? WqPt : WqGl;
        float*       dst = sel ? WqPtP : WqGlP;
        dst[((size_t)(k >> 2) * 256 + tid) * 4 + (k & 3)] = src[(size_t)tid * 256 + k];
        return;
    }

    const int tx = tid & 15, ty = tid >> 4;
    const int ml = tid >> 2;
    const int kb = (tid & 3) << 2;

    const int x = blockIdx.x;
    const int xcd = x & 7;
    const int j = x >> 3;
    const int mt = xcd * 100 + (j >> 3);
    const int sel = (j >> 2) & 1;
    const int nt = j & 3;
    const float* W    = sel ? Wpt : Wgl;
    const float* bias = sel ? bpt : bgl;
    float*       Eo   = sel ? Ept : Egl;
    const int m0 = mt * 64, n0 = nt * 64;

    float4 a4 = *(const float4*)(A + (size_t)(m0 + ml) * 256 + kb);
    float4 b4 = *(const float4*)(W + (size_t)(n0 + ml) * 256 + kb);

    float acc[4][4] = {};
    for (int k0 = 0; k0 < 256; k0 += 16) {
        As[kb+0][ml] = a4.x; As[kb+1][ml] = a4.y; As[kb+2][ml] = a4.z; As[kb+3][ml] = a4.w;
        Bs[kb+0][ml] = b4.x; Bs[kb+1][ml] = b4.y; Bs[kb+2][ml] = b4.z; Bs[kb+3][ml] = b4.w;
        __syncthreads();
        int k1 = k0 + 16;
        if (k1 < 256) {
            a4 = *(const float4*)(A + (size_t)(m0 + ml) * 256 + k1 + kb);
            b4 = *(const float4*)(W + (size_t)(n0 + ml) * 256 + k1 + kb);
        }
#pragma unroll
        for (int kk = 0; kk < 16; kk++) {
            float4 av = *(const float4*)(&As[kk][ty << 2]);
            float4 bv = *(const float4*)(&Bs[kk][tx << 2]);
            float a_[4] = {av.x, av.y, av.z, av.w};
            float b_[4] = {bv.x, bv.y, bv.z, bv.w};
#pragma unroll
        for (int i = 0; i < 4; i++)
#pragma unroll
            for (int j2 = 0; j2 < 4; j2++) acc[i][j2] = fmaf(a_[i], b_[j2], acc[i][j2]);
        }
        __syncthreads();
    }
#pragma unroll
    for (int i = 0; i < 4; i++) {
        int m = m0 + (ty << 2) + i;
        int bb = m & (Bsz - 1);
        int ll = m >> 10;
#pragma unroll
        for (int j2 = 0; j2 < 4; j2++) {
            int n = n0 + (tx << 2) + j2;
            Eo[(size_t)bb * Lsz * Hsz + (size_t)ll * Hsz + n] = acc[i][j2] + bias[n];
        }
    }
}

// ============================================================
// K1: fused LSTM, 32 rows x 32 gate-cols (8 hh x 4 gates) per block
// -> grid (32,32) = 1024 blocks = 4 blocks/CU (was 2: occupancy-
// starved).  Each thread owns ONE (m,hh) output and its 4 gate
// accumulators; the per-output accumulation chain is single-acc,
// ascending k in the identical 16-wide tile order -> bit-identical
// h/c to the verified kernel.  Register prefetch as before.
// ============================================================
__global__ __launch_bounds__(256) void lstm_fused(
    const float* __restrict__ dec, const float* __restrict__ hprev,
    const float* __restrict__ cin,
    const float* __restrict__ Wih, const float* __restrict__ Whh,
    const float* __restrict__ bih, const float* __restrict__ bhh,
    float* __restrict__ hout, float* __restrict__ cout)
{
    __shared__ __align__(16) float As[16][36];
    __shared__ __align__(16) float Bs[16][36];
    const int tid = threadIdx.x;
    const int tx = tid & 7;                  // hh offset [0,8)
    const int ty = tid >> 3;                 // m row     [0,32)
    const int mlA = tid >> 3;                // A stage row [0,32)
    const int kbA = (tid & 7) << 1;          // {0,2,..,14}
    const int mlB = tid >> 3;                // B stage wrow idx [0,32)
    const int kbB = (tid & 7) << 1;
    const int m0  = blockIdx.x * 32;
    const int hh0 = blockIdx.y * 8;
    const int wrow = ((mlB >> 3) << 8) + hh0 + (mlB & 7);   // gate*256 + hh
    const int pcol = ((mlB & 7) << 2) + (mlB >> 3);         // hcol*4 + gate

    float2 a2 = *(const float2*)(dec + (size_t)(m0 + mlA) * 256 + kbA);
    float2 b2 = *(const float2*)(Wih + (size_t)wrow * 256 + kbB);

    float acc[4] = {};
    for (int k0 = 0; k0 < 512; k0 += 16) {
        As[kbA+0][mlA] = a2.x; As[kbA+1][mlA] = a2.y;
        Bs[kbB+0][pcol] = b2.x; Bs[kbB+1][pcol] = b2.y;
        __syncthreads();
        int k1 = k0 + 16;
        if (k1 < 512) {
            const float* Ap = (k1 < 256) ? dec : hprev;
            const float* Wp = (k1 < 256) ? Wih : Whh;
            int kk0 = k1 & 255;
            a2 = *(const float2*)(Ap + (size_t)(m0 + mlA) * 256 + kk0 + kbA);
            b2 = *(const float2*)(Wp + (size_t)wrow * 256 + kk0 + kbB);
        }
#pragma unroll
        for (int kk = 0; kk < 16; kk++) {
            float av = As[kk][ty];
            float4 bv = *(const float4*)(&Bs[kk][tx << 2]);
            acc[0] = fmaf(av, bv.x, acc[0]);
            acc[1] = fmaf(av, bv.y, acc[1]);
            acc[2] = fmaf(av, bv.z, acc[2]);
            acc[3] = fmaf(av, bv.w, acc[3]);
        }
        __syncthreads();
    }

    const int hh = hh0 + tx;
    const int m  = m0 + ty;
    const float bi0 = bih[hh]       + bhh[hh];
    const float bf  = bih[256 + hh] + bhh[256 + hh];
    const float bg  = bih[512 + hh] + bhh[512 + hh];
    const float bo  = bih[768 + hh] + bhh[768 + hh];
    float gi = acc[0] + bi0;
    float gf = acc[1] + bf;
    float gc = acc[2] + bg;
    float go = acc[3] + bo;
    float ii = 1.0f / (1.0f + expf(-gi));
    float ff = 1.0f / (1.0f + expf(-gf));
    float oo = 1.0f / (1.0f + expf(-go));
    float c2 = ff * cin[(size_t)m * 256 + hh] + ii * tanhf(gc);
    hout[(size_t)m * 256 + hh] = oo * tanhf(c2);
    cout[(size_t)m * 256 + hh] = c2;
}

// ============================================================
// K2: fused glimpse + pointer attention, ONE row per block
// (1024 blocks) — byte-identical chains to the verified 4.14ms
// kernel.  Mask read is guarded by t>0 (mask array starts
// uninitialized; at t=0 the reference mask is all-false).
// ============================================================
__global__ __launch_bounds__(256) void attn_row(
    const float* __restrict__ h,
    const float* __restrict__ WqGlP, const float* __restrict__ glbq,
    const float* __restrict__ e_gl, const float* __restrict__ glv,
    const float* __restrict__ WqPtP, const float* __restrict__ ptbq,
    const float* __restrict__ e_pt, const float* __restrict__ ptv,
    int* __restrict__ mask, float* __restrict__ out, int t,
    float* __restrict__ dec, const float* __restrict__ emb)
{
    __shared__ __align__(16) float h_s[256];
    __shared__ __align__(16) float q_s[256];
    __shared__ __align__(16) float g_s[256];
    __shared__ float u_s[64];
    __shared__ float p_s[64];
    __shared__ int sel_s;

    const int tid = threadIdx.x;
    const int lane = tid & 63, wave = tid >> 6;
    const int b = blockIdx.x;

    h_s[tid] = h[(size_t)b * 256 + tid];
    __syncthreads();

    // ---- glimpse query matvec (packed weights) ----
    {
        float q = glbq[tid];
        const float4* Wp = (const float4*)WqGlP;
#pragma unroll 8
        for (int k4 = 0; k4 < 64; k4++) {
            float4 w  = Wp[(size_t)k4 * 256 + tid];
            float4 hv = ((const float4*)h_s)[k4];
            q = fmaf(hv.x, w.x, q);
            q = fmaf(hv.y, w.y, q);
            q = fmaf(hv.z, w.z, q);
            q = fmaf(hv.w, w.w, q);
        }
        q_s[tid] = q;
    }
    __syncthreads();

    const float* ebg = e_gl + (size_t)b * Lsz * 256;
    {
        const float4 q4 = ((const float4*)q_s)[lane];
        const float4 v4 = ((const float4*)glv)[lane];
#pragma unroll
        for (int lp = 0; lp < 13; lp++) {
            const int l = lp * 4 + wave;
            float x = 0.0f;
            if (l < Lsz) {
                float4 e4 = *(const float4*)(ebg + (size_t)l * 256 + (lane << 2));
                x  = v4.x * tanhf(q4.x + e4.x);
                x += v4.y * tanhf(q4.y + e4.y);
                x += v4.z * tanhf(q4.z + e4.z);
                x += v4.w * tanhf(q4.w + e4.w);
            }
#pragma unroll
            for (int o = 32; o > 0; o >>= 1) x += __shfl_xor(x, o, 64);
            if (lane == 0 && l < Lsz) u_s[l] = x;
        }
    }
    __syncthreads();

    // ---- glimpse softmax (wave 0, lane-parallel) ----
    if (wave == 0) {
        const int l = lane;
        const int ml = (l < Lsz && t > 0) ? mask[b * Lsz + l] : 0;
        float logit = (l < Lsz) ? (ml ? NEGV : u_s[l]) : -1e30f;
        float m = logit;
#pragma unroll
        for (int o = 32; o > 0; o >>= 1) m = fmaxf(m, __shfl_xor(m, o, 64));
        float ex = (l < Lsz) ? expf(logit - m) : 0.0f;
        float den = ex;
#pragma unroll
        for (int o = 32; o > 0; o >>= 1) den += __shfl_xor(den, o, 64);
        if (l < Lsz) p_s[l] = ex / den;
    }
    __syncthreads();

    // ---- glimpse mix (L2-hot re-read, exact l order) ----
    {
        float acc = 0.0f;
        const float* ebh = ebg + tid;
#pragma unroll
        for (int l = 0; l < Lsz; l++)
            acc = fmaf(p_s[l], ebh[(size_t)l * 256], acc);
        g_s[tid] = acc;
    }
    __syncthreads();

    // ---- pointer query matvec (packed weights) ----
    {
        float p = ptbq[tid];
        const float4* Wp = (const float4*)WqPtP;
#pragma unroll 8
        for (int k4 = 0; k4 < 64; k4++) {
            float4 w  = Wp[(size_t)k4 * 256 + tid];
            float4 gv = ((const float4*)g_s)[k4];
            p = fmaf(gv.x, w.x, p);
            p = fmaf(gv.y, w.y, p);
            p = fmaf(gv.z, w.z, p);
            p = fmaf(gv.w, w.w, p);
        }
        q_s[tid] = p;
    }
    __syncthreads();

    const float* ebp = e_pt + (size_t)b * Lsz * 256;
    {
        const float4 q4 = ((const float4*)q_s)[lane];
        const float4 v4 = ((const float4*)ptv)[lane];
#pragma unroll
        for (int lp = 0; lp < 13; lp++) {
            const int l = lp * 4 + wave;
            float x = 0.0f;
            if (l < Lsz) {
                float4 e4 = *(const float4*)(ebp + (size_t)l * 256 + (lane << 2));
                x  = v4.x * tanhf(q4.x + e4.x);
                x += v4.y * tanhf(q4.y + e4.y);
                x += v4.z * tanhf(q4.z + e4.z);
                x += v4.w * tanhf(q4.w + e4.w);
            }
#pragma unroll
            for (int o = 32; o > 0; o >>= 1) x += __shfl_xor(x, o, 64);
            if (lane == 0 && l < Lsz) u_s[l] = x;
        }
    }
    __syncthreads();

    // ---- pointer softmax + argmax + log_p + mask update (wave 0) ----
    if (wave == 0) {
        const int l = lane;
        const int ml = (l < Lsz && t > 0) ? mask[b * Lsz + l] : 0;
        float logit;
        if (l < Lsz) {
            float u = u_s[l];
            logit = 10.0f * tanhf(u);
            if (ml) logit = NEGV;
        } else logit = -1e30f;

        float m = logit;
#pragma unroll
        for (int o = 32; o > 0; o >>= 1) m = fmaxf(m, __shfl_xor(m, o, 64));
        float ex = (l < Lsz) ? expf(logit - m) : 0.0f;
        float den = ex;
#pragma unroll
        for (int o = 32; o > 0; o >>= 1) den += __shfl_xor(den, o, 64);

        // argmax with first-index tie-break
        float av = logit; int ai = (l < Lsz) ? l : 63;
#pragma unroll
        for (int o = 32; o > 0; o >>= 1) {
            float ov = __shfl_xor(av, o, 64);
            int   oi = __shfl_xor(ai, o, 64);
            if (ov > av || (ov == av && oi < ai)) { av = ov; ai = oi; }
        }
        const float lse = m + logf(den);
        if (l < Lsz)
            out[(size_t)b * Lsz * Lsz + (size_t)t * Lsz + l] = logit - lse;
        if (l == 0) {
            out[(size_t)Bsz * Lsz * Lsz + (size_t)b * Lsz + t] = (float)ai;
            sel_s = ai;
        }
        int newm = ml | (l == ai);
        unsigned long long bal = __ballot(l >= Lsz ? 1 : newm);
        int all = (bal == 0xFFFFFFFFFFFFFFFFull);
        if (l < Lsz) mask[b * Lsz + l] = (all && l == Lsz - 1) ? 0 : newm;
    }
    __syncthreads();

    // ---- gather next decoder input ----
    {
        const int s = sel_s;
        dec[(size_t)b * 256 + tid] = emb[(size_t)s * Bsz * 256 + (size_t)b * 256 + tid];
    }
}

// ============================================================
extern "C" void kernel_launch(void* const* d_in, const int* in_sizes, int n_in,
                              void* d_out, int out_size, void* d_ws, size_t ws_size,
                              hipStream_t stream) {
    const float* decoder_input = (const float*)d_in[0];
    const float* emb           = (const float*)d_in[1];   // [L,B,E]
    const float* h0            = (const float*)d_in[2];
    const float* c0            = (const float*)d_in[3];
    const float* context       = (const float*)d_in[4];   // [L,B,H]
    const float* Wih    = (const float*)d_in[6];
    const float* Whh    = (const float*)d_in[7];
    const float* bih    = (const float*)d_in[8];
    const float* bhh    = (const float*)d_in[9];
    const float* glWq   = (const float*)d_in[10];
    const float* glbq   = (const float*)d_in[11];
    const float* glWref = (const float*)d_in[12];
    const float* glbref = (const float*)d_in[13];
    const float* glv    = (const float*)d_in[14];
    const float* ptWq   = (const float*)d_in[15];
    const float* ptbq   = (const float*)d_in[16];
    const float* ptWref = (const float*)d_in[17];
    const float* ptbref = (const float*)d_in[18];
    const float* ptv    = (const float*)d_in[19];

    float* out = (float*)d_out;

    // workspace layout (floats)
    float* ws    = (float*)d_ws;
    float* e_gl  = ws;                                    // [B,L,H]
    float* e_pt  = e_gl + (size_t)Bsz * Lsz * Hsz;        // [B,L,H]
    float* WqGlP = e_pt + (size_t)Bsz * Lsz * Hsz;        // [H,H] packed
    float* WqPtP = WqGlP + (size_t)Hsz * Hsz;
    float* hb0   = WqPtP + (size_t)Hsz * Hsz;
    float* hb1   = hb0 + (size_t)Bsz * Hsz;
    float* cb0   = hb1 + (size_t)Bsz * Hsz;
    float* cb1   = cb0 + (size_t)Bsz * Hsz;
    float* dec   = cb1 + (size_t)Bsz * Hsz;
    int*   mask  = (int*)(dec + (size_t)Bsz * Esz);       // [B,L]

    float* hbuf[2] = {hb0, hb1};
    float* cbuf[2] = {cb0, cb1};

    // one-time: e-projection GEMMs + Wq pack, single dispatch
    eproj_pack<<<dim3(6912), dim3(256), 0, stream>>>(
        context, glWref, glbref, e_gl, ptWref, ptbref, e_pt,
        glWq, ptWq, WqGlP, WqPtP);

    for (int t = 0; t < Lsz; t++) {
        const float* Ain = (t == 0) ? decoder_input : dec;
        const float* hin = (t == 0) ? h0 : hbuf[(t + 1) & 1];
        const float* cin = (t == 0) ? c0 : cbuf[(t + 1) & 1];
        float* hout = hbuf[t & 1];
        float* cout = cbuf[t & 1];

        lstm_fused<<<dim3(32, 32), dim3(256), 0, stream>>>(
            Ain, hin, cin, Wih, Whh, bih, bhh, hout, cout);

        attn_row<<<dim3(1024), dim3(256), 0, stream>>>(
            hout, WqGlP, glbq, e_gl, glv, WqPtP, ptbq, e_pt, ptv,
            mask, out, t, dec, emb);
    }
}